// Round 11
// baseline (330.012 us; speedup 1.0000x reference)
//
#include <hip/hip_runtime.h>
#include <stdint.h>

// Problem constants: B=8, H=W=64, C=256
#define NB    8
#define NTOK  4096          // H*W tokens per batch
#define TOK   32768         // NB*NTOK
#define CDIM  256
#define BQ    128           // queries per block (flash): 32 per wave-pair
#define BK    64            // keys per LDS tile (flash); split 32/32 across wave halves
#define NT    (NTOK / BK)   // 64 key tiles

#define KPITCH 264          // Ks row pitch in shorts (pad +8, baked into k2 global)
#define VPITCH 68           // Vs row pitch in shorts (pad +4, baked into vt2 global)
#define KTILE_SH (BK * KPITCH)     // 16896 shorts = 33792 B
#define VTILE_SH (CDIM * VPITCH)   // 17408 shorts = 34816 B
#define KCH   33
#define VCH   34
#define TOTCH (KCH + VCH)   // 67 1-KB DMA chunks per tile

typedef __attribute__((ext_vector_type(8))) short bf16x8;   // 8 bf16 = 4 VGPRs
typedef __attribute__((ext_vector_type(4))) float f32x4;    // MFMA C/D frag

#define SSCALE 0.09016844f   // C^-0.5 * log2(e) = 0.0625 * 1.442695

static __device__ __forceinline__ unsigned short f2bf(float f) {
    union { float f; unsigned u; } v; v.f = f;
    unsigned r = v.u + 0x7fffu + ((v.u >> 16) & 1u);   // RNE
    return (unsigned short)(r >> 16);
}

// async global->LDS DMA: 16 B/lane, LDS dest = uniform base + lane*16
static __device__ __forceinline__ void dma16(const unsigned short* g, unsigned short* l) {
    __builtin_amdgcn_global_load_lds(
        (const __attribute__((address_space(1))) unsigned int*)g,
        (__attribute__((address_space(3))) unsigned int*)l,
        16, 0, 0);
}

// ---------------- prep: weight transpose + bf16 cast -------------------------
__global__ __launch_bounds__(256) void wtrans_kernel(
        const float* __restrict__ w0, const float* __restrict__ w1,
        const float* __restrict__ w2, const float* __restrict__ w3,
        unsigned short* __restrict__ wt) {
    int id = blockIdx.x;              // 0..1023
    int m = id >> 8, dd = id & 255;
    const float* src = (m == 0) ? w0 : (m == 1) ? w1 : (m == 2) ? w2 : w3;
    wt[m * (CDIM * CDIM) + dd * CDIM + threadIdx.x] = f2bf(src[threadIdx.x * CDIM + dd]);
}

// ---------------- fused LN + Q+K+V projection, token-exclusive blocks --------
// grid 1024, 256 thr / 4 waves. Block blk owns tokens [blk*32, +32): LN is
// computed ONCE cooperatively into an LDS h-tile (x read exactly once —
// fixes round-9's 8x x re-read), then wave w computes output columns
// nt = w*4..w*4+3 of all three projections from LDS A-fragments.
// Q/K swapped MFMA -> packed 8B stores; V key-columns PERMUTED within the
// block's 32-key half (slot = quad*8 + s*4 + r) for flash's register P.
// K/V tile mapping: tile = blk>>1, half = blk&1. LDS 35.3KB -> 4 blocks/CU.
__global__ __launch_bounds__(256, 4) void lnqkv_kernel(
        const float* __restrict__ x,
        const float* __restrict__ gamma,
        const float* __restrict__ beta,
        const unsigned short* __restrict__ wts,
        const float* __restrict__ bq,
        const float* __restrict__ bk,
        const float* __restrict__ bv,
        unsigned short* __restrict__ q_bf,
        unsigned short* __restrict__ k2,
        unsigned short* __restrict__ vt2) {
    __shared__ unsigned short HT[32][KPITCH];   // 16896 B  (LN'd tokens, bf16)
    __shared__ unsigned short VT[256][36];      // 18432 B  (V^T half-tile)
    int tid = threadIdx.x;
    int w = tid >> 6, lane = tid & 63, quad = lane >> 4, l16 = lane & 15;
    int blk = blockIdx.x;
    int tok_base = blk * 32;
    int nt0 = w * 4;

    // ---- LN once: wave w -> tokens w*8..+8; lane&7 -> 32-channel slice
    {
        int t_loc = w * 8 + (lane >> 3);
        int cg = (lane & 7) * 32;
        const float* xr = x + (size_t)(tok_base + t_loc) * CDIM + cg;
        float s1 = 0.f, s2 = 0.f;
        float4 xv[8];
        #pragma unroll
        for (int j = 0; j < 8; ++j) {
            xv[j] = ((const float4*)xr)[j];
            s1 += xv[j].x + xv[j].y + xv[j].z + xv[j].w;
            s2 += xv[j].x * xv[j].x + xv[j].y * xv[j].y
                + xv[j].z * xv[j].z + xv[j].w * xv[j].w;
        }
        #pragma unroll
        for (int off = 1; off < 8; off <<= 1) {
            s1 += __shfl_xor(s1, off, 64);
            s2 += __shfl_xor(s2, off, 64);
        }
        float mean = s1 * (1.0f / 256.0f);
        float var  = s2 * (1.0f / 256.0f) - mean * mean;   // x~N(0,1): no cancellation risk
        float rstd = rsqrtf(var + 1e-5f);
        #pragma unroll
        for (int j = 0; j < 8; j += 2) {
            float4 xa = xv[j], xb = xv[j + 1];
            float4 ga = ((const float4*)(gamma + cg))[j];
            float4 gb = ((const float4*)(gamma + cg))[j + 1];
            float4 ba = ((const float4*)(beta + cg))[j];
            float4 bb4 = ((const float4*)(beta + cg))[j + 1];
            union { uint4 u; unsigned short us[8]; } pk;
            pk.us[0] = f2bf((xa.x - mean) * rstd * ga.x + ba.x);
            pk.us[1] = f2bf((xa.y - mean) * rstd * ga.y + ba.y);
            pk.us[2] = f2bf((xa.z - mean) * rstd * ga.z + ba.z);
            pk.us[3] = f2bf((xa.w - mean) * rstd * ga.w + ba.w);
            pk.us[4] = f2bf((xb.x - mean) * rstd * gb.x + bb4.x);
            pk.us[5] = f2bf((xb.y - mean) * rstd * gb.y + bb4.y);
            pk.us[6] = f2bf((xb.z - mean) * rstd * gb.z + bb4.z);
            pk.us[7] = f2bf((xb.w - mean) * rstd * gb.w + bb4.w);
            *(uint4*)(&HT[t_loc][cg + j * 4]) = pk.u;
        }
    }
    __syncthreads();

    bf16x8 afr[2][8];
    #pragma unroll
    for (int s = 0; s < 2; ++s)
        #pragma unroll
        for (int kk = 0; kk < 8; ++kk)
            afr[s][kk] = *(const bf16x8*)(&HT[s * 16 + l16][kk * 32 + quad * 8]);

    // ---- Q (swapped; pre-scaled by SSCALE; 8B packed stores)
    {
        const unsigned short* wq_t = wts;
        #pragma unroll
        for (int ntl = 0; ntl < 4; ++ntl) {
            int nt = nt0 + ntl;
            f32x4 acc0 = {0.f, 0.f, 0.f, 0.f};
            f32x4 acc1 = {0.f, 0.f, 0.f, 0.f};
            #pragma unroll
            for (int kk = 0; kk < 8; ++kk) {
                bf16x8 bfr = *(const bf16x8*)(wq_t + (size_t)(nt * 16 + l16) * CDIM + kk * 32 + quad * 8);
                acc0 = __builtin_amdgcn_mfma_f32_16x16x32_bf16(bfr, afr[0][kk], acc0, 0, 0, 0);
                acc1 = __builtin_amdgcn_mfma_f32_16x16x32_bf16(bfr, afr[1][kk], acc1, 0, 0, 0);
            }
            int d0 = nt * 16 + quad * 4;
            float4 b4 = *(const float4*)(bq + d0);
            ushort4 o0, o1;
            o0.x = f2bf((acc0[0] + b4.x) * SSCALE); o0.y = f2bf((acc0[1] + b4.y) * SSCALE);
            o0.z = f2bf((acc0[2] + b4.z) * SSCALE); o0.w = f2bf((acc0[3] + b4.w) * SSCALE);
            o1.x = f2bf((acc1[0] + b4.x) * SSCALE); o1.y = f2bf((acc1[1] + b4.y) * SSCALE);
            o1.z = f2bf((acc1[2] + b4.z) * SSCALE); o1.w = f2bf((acc1[3] + b4.w) * SSCALE);
            *(ushort4*)(q_bf + (size_t)(tok_base + l16) * CDIM + d0)      = o0;
            *(ushort4*)(q_bf + (size_t)(tok_base + 16 + l16) * CDIM + d0) = o1;
        }
    }
    // ---- K (swapped; tile blk>>1, rows (blk&1)*32 + s*16 + l16)
    {
        const unsigned short* wk_t = wts + CDIM * CDIM;
        unsigned short* kdst = k2 + (size_t)(blk >> 1) * KTILE_SH;
        int key0 = (blk & 1) * 32 + l16;
        #pragma unroll
        for (int ntl = 0; ntl < 4; ++ntl) {
            int nt = nt0 + ntl;
            f32x4 acc0 = {0.f, 0.f, 0.f, 0.f};
            f32x4 acc1 = {0.f, 0.f, 0.f, 0.f};
            #pragma unroll
            for (int kk = 0; kk < 8; ++kk) {
                bf16x8 bfr = *(const bf16x8*)(wk_t + (size_t)(nt * 16 + l16) * CDIM + kk * 32 + quad * 8);
                acc0 = __builtin_amdgcn_mfma_f32_16x16x32_bf16(bfr, afr[0][kk], acc0, 0, 0, 0);
                acc1 = __builtin_amdgcn_mfma_f32_16x16x32_bf16(bfr, afr[1][kk], acc1, 0, 0, 0);
            }
            int d0 = nt * 16 + quad * 4;
            float4 b4 = *(const float4*)(bk + d0);
            ushort4 o0, o1;
            o0.x = f2bf(acc0[0] + b4.x); o0.y = f2bf(acc0[1] + b4.y);
            o0.z = f2bf(acc0[2] + b4.z); o0.w = f2bf(acc0[3] + b4.w);
            o1.x = f2bf(acc1[0] + b4.x); o1.y = f2bf(acc1[1] + b4.y);
            o1.z = f2bf(acc1[2] + b4.z); o1.w = f2bf(acc1[3] + b4.w);
            *(ushort4*)(kdst + (size_t)key0 * KPITCH + d0)        = o0;
            *(ushort4*)(kdst + (size_t)(key0 + 16) * KPITCH + d0) = o1;
        }
    }
    // ---- V (unswapped; keys permuted within the 32-half: k32 = s*16+quad*4+r
    //      -> slot quad*8 + s*4 + r; wave w covers d in [w*64, w*64+64))
    {
        const unsigned short* wv_t = wts + 2 * CDIM * CDIM;
        #pragma unroll
        for (int ntl = 0; ntl < 4; ++ntl) {
            int nt = nt0 + ntl;
            f32x4 acc0 = {0.f, 0.f, 0.f, 0.f};
            f32x4 acc1 = {0.f, 0.f, 0.f, 0.f};
            #pragma unroll
            for (int kk = 0; kk < 8; ++kk) {
                bf16x8 bfr = *(const bf16x8*)(wv_t + (size_t)(nt * 16 + l16) * CDIM + kk * 32 + quad * 8);
                acc0 = __builtin_amdgcn_mfma_f32_16x16x32_bf16(afr[0][kk], bfr, acc0, 0, 0, 0);
                acc1 = __builtin_amdgcn_mfma_f32_16x16x32_bf16(afr[1][kk], bfr, acc1, 0, 0, 0);
            }
            int d = nt * 16 + l16;
            float bb = bv[d];
            #pragma unroll
            for (int r = 0; r < 4; ++r) {
                VT[d][quad * 8 + r]     = f2bf(acc0[r] + bb);  // k32 = quad*4+r      (s=0)
                VT[d][quad * 8 + 4 + r] = f2bf(acc1[r] + bb);  // k32 = 16+quad*4+r   (s=1)
            }
        }
    }
    __syncthreads();
    // coalesced copy-out: 256 rows x 64 B -> vt2 tile (blk>>1), col (blk&1)*32
    {
        unsigned short* vdst = vt2 + (size_t)(blk >> 1) * VTILE_SH + (blk & 1) * 32;
        #pragma unroll
        for (int i = 0; i < 4; ++i) {
            int idx = i * 256 + tid;          // 0..1023
            int row = idx >> 2, c = idx & 3;
            *(uint4*)(vdst + (size_t)row * VPITCH + c * 8) = *(const uint4*)(&VT[row][c * 8]);
        }
    }
}

// ---------------- Flash attention + fused output projection ------------------
// BYTE-IDENTICAL to round 10 (measured 198.1 us): distinct __shared__ arrays,
// swapped QK^T, register-resident P, permuted V, __syncthreads pipeline,
// s_setprio(1) around MFMA clusters, fused channel-split oproj epilogue.
#define DMA_TILE(KS, VS, ktn)                                                        \
    {                                                                                \
        const unsigned short* gk = k2 + (size_t)(b * NT + (ktn)) * KTILE_SH;         \
        const unsigned short* gv = vt2 + (size_t)(b * NT + (ktn)) * VTILE_SH;        \
        for (int c = w; c < TOTCH; c += 8) {                                         \
            if (c < KCH) dma16(gk + c * 512 + lane * 8, &KS[0][0] + c * 512);        \
            else dma16(gv + (c - KCH) * 512 + lane * 8, &VS[0][0] + (c - KCH) * 512);\
        }                                                                            \
    }

#define COMPUTE_TILE(KS, VS)                                                         \
    {                                                                                \
        f32x4 sfr[2][2];                                                             \
        __builtin_amdgcn_s_setprio(1);                                               \
        _Pragma("unroll")                                                            \
        for (int nt = 0; nt < 2; ++nt) {                                             \
            f32x4 a0 = {0.f, 0.f, 0.f, 0.f};                                         \
            f32x4 a1 = {0.f, 0.f, 0.f, 0.f};                                         \
            _Pragma("unroll")                                                        \
            for (int kk = 0; kk < 8; ++kk) {                                         \
                bf16x8 kb = *(const bf16x8*)(&KS[kh * 32 + nt * 16 + l16][kk * 32 + quad * 8]); \
                a0 = __builtin_amdgcn_mfma_f32_16x16x32_bf16(kb, qfr[0][kk], a0, 0, 0, 0);      \
                a1 = __builtin_amdgcn_mfma_f32_16x16x32_bf16(kb, qfr[1][kk], a1, 0, 0, 0);      \
            }                                                                        \
            sfr[0][nt] = a0; sfr[1][nt] = a1;                                        \
        }                                                                            \
        __builtin_amdgcn_s_setprio(0);                                               \
        int4 pwv[2];                                                                 \
        _Pragma("unroll")                                                            \
        for (int s = 0; s < 2; ++s) {                                                \
            unsigned pw[4];                                                          \
            _Pragma("unroll")                                                        \
            for (int nt = 0; nt < 2; ++nt)                                           \
                _Pragma("unroll")                                                    \
                for (int h = 0; h < 2; ++h) {                                        \
                    float plo = exp2f(sfr[s][nt][2 * h]);                            \
                    float phi = exp2f(sfr[s][nt][2 * h + 1]);                        \
                    lacc[s] += plo + phi;                                            \
                    pw[nt * 2 + h] = (__float_as_uint(plo) >> 16)                    \
                                   | (__float_as_uint(phi) & 0xffff0000u);           \
                }                                                                    \
            pwv[s] = make_int4(pw[0], pw[1], pw[2], pw[3]);                          \
        }                                                                            \
        bf16x8 pfr0 = *(bf16x8*)&pwv[0];                                             \
        bf16x8 pfr1 = *(bf16x8*)&pwv[1];                                             \
        __builtin_amdgcn_s_setprio(1);                                               \
        _Pragma("unroll")                                                            \
        for (int nt2 = 0; nt2 < 16; ++nt2) {                                         \
            bf16x8 vb = *(const bf16x8*)(&VS[nt2 * 16 + l16][kh * 32 + quad * 8]);   \
            O[0][nt2] = __builtin_amdgcn_mfma_f32_16x16x32_bf16(pfr0, vb, O[0][nt2], 0, 0, 0);  \
            O[1][nt2] = __builtin_amdgcn_mfma_f32_16x16x32_bf16(pfr1, vb, O[1][nt2], 0, 0, 0);  \
        }                                                                            \
        __builtin_amdgcn_s_setprio(0);                                               \
    }

__global__ __launch_bounds__(512, 2) void flash_kernel(
        const unsigned short* __restrict__ q_bf,
        const unsigned short* __restrict__ k2,
        const unsigned short* __restrict__ vt2,
        const unsigned short* __restrict__ wo_t,
        const float* __restrict__ bo,
        const float* __restrict__ x,
        float* __restrict__ out) {
    __shared__ unsigned short Ks0[BK][KPITCH];    // 33792 B
    __shared__ unsigned short Ks1[BK][KPITCH];    // 33792 B
    __shared__ unsigned short Vs0[CDIM][VPITCH];  // 34816 B
    __shared__ unsigned short Vs1[CDIM][VPITCH];  // 34816 B
    __shared__ float sLbuf[512];                  // 2048 B  (total 139.3 KB)

    int tid = threadIdx.x;
    int w = tid >> 6, lane = tid & 63, quad = lane >> 4, l16 = lane & 15;
    int kh = w >> 2;        // key half of each tile
    int wq = w & 3;         // q-row group (shared with wave w^4)
    int bid = blockIdx.x;
    int b = bid & 7;        // XCD swizzle: same batch -> same XCD L2
    int qtile = bid >> 3;
    int qrow = qtile * BQ + wq * 32;
    const size_t bbase = (size_t)b * NTOK * CDIM;

    bf16x8 qfr[2][8];
    #pragma unroll
    for (int s = 0; s < 2; ++s)
        #pragma unroll
        for (int kk = 0; kk < 8; ++kk)
            qfr[s][kk] = *(const bf16x8*)(q_bf + bbase + (size_t)(qrow + s * 16 + l16) * CDIM + kk * 32 + quad * 8);

    f32x4 O[2][16];
    #pragma unroll
    for (int s = 0; s < 2; ++s)
        #pragma unroll
        for (int i = 0; i < 16; ++i) O[s][i] = (f32x4){0.f, 0.f, 0.f, 0.f};
    float lacc[2] = {0.f, 0.f};   // per-lane: q = s*16+l16, this quad's 8 keys/tile

    DMA_TILE(Ks0, Vs0, 0);
    __syncthreads();

    for (int kt2 = 0; kt2 < NT; kt2 += 2) {
        DMA_TILE(Ks1, Vs1, kt2 + 1);
        COMPUTE_TILE(Ks0, Vs0);
        __syncthreads();
        if (kt2 + 2 < NT) DMA_TILE(Ks0, Vs0, kt2 + 2);
        COMPUTE_TILE(Ks1, Vs1);
        __syncthreads();
    }

    // ---- epilogue 1: combine wave pairs (key halves) through dead LDS buffers
    float* sO = (wq == 0) ? (float*)&Ks0[0][0] : (wq == 1) ? (float*)&Ks1[0][0]
              : (wq == 2) ? (float*)&Vs0[0][0] : (float*)&Vs1[0][0];
    float* sL = sLbuf + wq * 128;    // 2 x 64 floats per pair

    if (kh == 1) {
        #pragma unroll
        for (int s = 0; s < 2; ++s) {
            #pragma unroll
            for (int nt2 = 0; nt2 < 16; ++nt2)
                #pragma unroll
                for (int r = 0; r < 4; ++r)
                    sO[((s * 16 + nt2) * 4 + r) * 64 + lane] = O[s][nt2][r];
            sL[s * 64 + lane] = lacc[s];
        }
    }
    __syncthreads();
    if (kh == 0) {
        float lr[2][4];
        #pragma unroll
        for (int s = 0; s < 2; ++s) {
            float ls = lacc[s] + sL[s * 64 + lane];   // + pair's partial (same lane mapping)
            ls += __shfl_xor(ls, 16, 64);             // sum the 4 quad partials
            ls += __shfl_xor(ls, 32, 64);
            float li = 1.0f / ls;                     // full denom for q = s*16+l16
            #pragma unroll
            for (int r = 0; r < 4; ++r)
                lr[s][r] = __shfl(li, quad * 4 + r, 64);   // denom for O row quad*4+r
        }
        #pragma unroll
        for (int s = 0; s < 2; ++s)
            #pragma unroll
            for (int nt2 = 0; nt2 < 16; ++nt2)
                #pragma unroll
                for (int r = 0; r < 4; ++r)
                    O[s][nt2][r] = (O[s][nt2][r] + sO[((s * 16 + nt2) * 4 + r) * 64 + lane]) * lr[s][r];
    }
    __syncthreads();   // all sO reads done before attn staging overwrites Ks0/Ks1

    // ---- epilogue 2: kh0 waves stage normalized bf16 attn rows.
    // Row t = wq*32 + s*16 + quad*4 + r (0..127): t<64 -> Ks0[t], else Ks1[t-64].
    if (kh == 0) {
        if (wq < 2) {
            #pragma unroll
            for (int s = 0; s < 2; ++s)
                #pragma unroll
                for (int nt2 = 0; nt2 < 16; ++nt2)
                    #pragma unroll
                    for (int r = 0; r < 4; ++r)
                        Ks0[(wq & 1) * 32 + s * 16 + quad * 4 + r][nt2 * 16 + l16] = f2bf(O[s][nt2][r]);
        } else {
            #pragma unroll
            for (int s = 0; s < 2; ++s)
                #pragma unroll
                for (int nt2 = 0; nt2 < 16; ++nt2)
                    #pragma unroll
                    for (int r = 0; r < 4; ++r)
                        Ks1[(wq & 1) * 32 + s * 16 + quad * 4 + r][nt2 * 16 + l16] = f2bf(O[s][nt2][r]);
        }
    }
    __syncthreads();

    // ---- epilogue 3: fused oproj, channel-split. Wave w -> channels
    // nt = 2w, 2w+1 (16 each) for all 128 rows; weight frags hoisted.
    {
        bf16x8 wfr[2][8];
        #pragma unroll
        for (int t = 0; t < 2; ++t)
            #pragma unroll
            for (int kk = 0; kk < 8; ++kk)
                wfr[t][kk] = *(const bf16x8*)(wo_t + (size_t)((w * 2 + t) * 16 + l16) * CDIM + kk * 32 + quad * 8);
        float bb0 = bo[(w * 2 + 0) * 16 + l16];
        float bb1 = bo[(w * 2 + 1) * 16 + l16];
        int tok0 = qtile * BQ;
        #pragma unroll
        for (int rg = 0; rg < 8; ++rg) {
            bf16x8 afr2[8];
            #pragma unroll
            for (int kk = 0; kk < 8; ++kk)
                afr2[kk] = (rg < 4)
                    ? *(const bf16x8*)(&Ks0[rg * 16 + l16][kk * 32 + quad * 8])
                    : *(const bf16x8*)(&Ks1[(rg - 4) * 16 + l16][kk * 32 + quad * 8]);
            f32x4 acc0 = {0.f, 0.f, 0.f, 0.f};
            f32x4 acc1 = {0.f, 0.f, 0.f, 0.f};
            #pragma unroll
            for (int kk = 0; kk < 8; ++kk) {
                acc0 = __builtin_amdgcn_mfma_f32_16x16x32_bf16(afr2[kk], wfr[0][kk], acc0, 0, 0, 0);
                acc1 = __builtin_amdgcn_mfma_f32_16x16x32_bf16(afr2[kk], wfr[1][kk], acc1, 0, 0, 0);
            }
            #pragma unroll
            for (int r = 0; r < 4; ++r) {
                size_t idx = bbase + (size_t)(tok0 + rg * 16 + quad * 4 + r) * CDIM;
                size_t i0 = idx + (w * 2 + 0) * 16 + l16;
                size_t i1 = idx + (w * 2 + 1) * 16 + l16;
                out[i0] = x[i0] + acc0[r] + bb0;
                out[i1] = x[i1] + acc1[r] + bb1;
            }
        }
    }
}

extern "C" void kernel_launch(void* const* d_in, const int* in_sizes, int n_in,
                              void* d_out, int out_size, void* d_ws, size_t ws_size,
                              hipStream_t stream) {
    const float* x     = (const float*)d_in[0];
    const float* gamma = (const float*)d_in[1];
    const float* beta  = (const float*)d_in[2];
    const float* wq    = (const float*)d_in[3];
    const float* bq    = (const float*)d_in[4];
    const float* wk    = (const float*)d_in[5];
    const float* bk    = (const float*)d_in[6];
    const float* wv    = (const float*)d_in[7];
    const float* bv    = (const float*)d_in[8];
    const float* wo    = (const float*)d_in[9];
    const float* bo    = (const float*)d_in[10];
    float* out = (float*)d_out;

    // workspace layout (bytes):
    //   q    @ 16,777,216 16,777,216
    //   k2   @ 33,554,432 17,301,504   (padded tiled K: 512 tiles x 64 x 264)
    //   vt2  @ 50,855,936 17,825,792   (padded tiled Vt: 512 tiles x 256 x 68, keys permuted)
    //   wt   @ 68,681,728    524,288   (4 transposed bf16 weight matrices)
    char* ws = (char*)d_ws;
    unsigned short* q_bf = (unsigned short*)(ws + 16777216);
    unsigned short* k2   = (unsigned short*)(ws + 33554432);
    unsigned short* vt2  = (unsigned short*)(ws + 50855936);
    unsigned short* wt   = (unsigned short*)(ws + 68681728);

    wtrans_kernel<<<1024, 256, 0, stream>>>(wq, wk, wv, wo, wt);
    lnqkv_kernel<<<1024, 256, 0, stream>>>(x, gamma, beta, wt, bq, bk, bv, q_bf, k2, vt2);
    flash_kernel<<<(NTOK / BQ) * NB, 512, 0, stream>>>(
        q_bf, k2, vt2, wt + 3 * (CDIM * CDIM), bo, x, out);
}

// Round 12
// 327.232 us; speedup vs baseline: 1.0085x; 1.0085x over previous
//
#include <hip/hip_runtime.h>
#include <stdint.h>

// Problem constants: B=8, H=W=64, C=256
#define NB    8
#define NTOK  4096          // H*W tokens per batch
#define TOK   32768         // NB*NTOK
#define CDIM  256
#define BQ    128           // queries per block (flash): 32 per wave-pair
#define BK    64            // keys per LDS tile (flash); split 32/32 across wave halves
#define NT    (NTOK / BK)   // 64 key tiles

#define KPITCH 264          // Ks row pitch in shorts (pad +8, baked into k2 global)
#define VPITCH 68           // Vs row pitch in shorts (pad +4, baked into vt2 global)
#define KTILE_SH (BK * KPITCH)     // 16896 shorts = 33792 B
#define VTILE_SH (CDIM * VPITCH)   // 17408 shorts = 34816 B
#define KCH   33
#define VCH   34
#define TOTCH (KCH + VCH)   // 67 1-KB DMA chunks per tile

typedef __attribute__((ext_vector_type(8))) short bf16x8;   // 8 bf16 = 4 VGPRs
typedef __attribute__((ext_vector_type(4))) float f32x4;    // MFMA C/D frag

#define SSCALE 0.09016844f   // C^-0.5 * log2(e) = 0.0625 * 1.442695

static __device__ __forceinline__ unsigned short f2bf(float f) {
    union { float f; unsigned u; } v; v.f = f;
    unsigned r = v.u + 0x7fffu + ((v.u >> 16) & 1u);   // RNE
    return (unsigned short)(r >> 16);
}

// async global->LDS DMA: 16 B/lane, LDS dest = uniform base + lane*16
static __device__ __forceinline__ void dma16(const unsigned short* g, unsigned short* l) {
    __builtin_amdgcn_global_load_lds(
        (const __attribute__((address_space(1))) unsigned int*)g,
        (__attribute__((address_space(3))) unsigned int*)l,
        16, 0, 0);
}

// ---------------- prep: LayerNorm (blocks 0..8191) + tiled weight transpose --
// Transpose now LDS-tiled: 64 blocks, each stages 16 W-rows with coalesced
// 1KB row reads into T[256][17] (odd pitch, conflict-free), then writes
// 32B-packed bf16 runs. Replaces the old column-read (4B/64B-line, 16x
// read amplification).
__global__ __launch_bounds__(256) void prep_kernel(
        const float* __restrict__ x,
        const float* __restrict__ gamma,
        const float* __restrict__ beta,
        const float* __restrict__ w0, const float* __restrict__ w1,
        const float* __restrict__ w2, const float* __restrict__ w3,
        unsigned short* __restrict__ h_bf,
        unsigned short* __restrict__ wt) {
    __shared__ float T[256][17];      // 17408 B (transpose staging; LN blocks unused)
    int bx = blockIdx.x;
    int tid = threadIdx.x;
    if (bx >= TOK / 4) {
        // tiled transpose: block id -> matrix m, row-group rg (16 rows of W)
        int id = bx - TOK / 4;        // 0..63
        int m = id >> 4, rg = id & 15;
        const float* src = (m == 0) ? w0 : (m == 1) ? w1 : (m == 2) ? w2 : w3;
        #pragma unroll
        for (int j = 0; j < 16; ++j)
            T[tid][j] = src[(rg * 16 + j) * CDIM + tid];   // coalesced 1KB row reads
        __syncthreads();
        unsigned short* dst = wt + m * (CDIM * CDIM) + tid * CDIM + rg * 16;
        #pragma unroll
        for (int q = 0; q < 4; ++q) {
            ushort4 o;
            o.x = f2bf(T[tid][q * 4 + 0]);
            o.y = f2bf(T[tid][q * 4 + 1]);
            o.z = f2bf(T[tid][q * 4 + 2]);
            o.w = f2bf(T[tid][q * 4 + 3]);
            ((ushort4*)dst)[q] = o;    // wt[m][dd=tid][rg*16+r] = W[rg*16+r][tid]
        }
        return;
    }
    int w = tid >> 6;
    int lane = tid & 63;
    int token = bx * 4 + w;
    const float4 xv = ((const float4*)(x + (size_t)token * CDIM))[lane];
    float s = xv.x + xv.y + xv.z + xv.w;
    #pragma unroll
    for (int off = 1; off < 64; off <<= 1) s += __shfl_xor(s, off, 64);
    float mean = s * (1.0f / 256.0f);
    float d0 = xv.x - mean, d1 = xv.y - mean, d2 = xv.z - mean, d3 = xv.w - mean;
    float ss = d0 * d0 + d1 * d1 + d2 * d2 + d3 * d3;
    #pragma unroll
    for (int off = 1; off < 64; off <<= 1) ss += __shfl_xor(ss, off, 64);
    float rstd = rsqrtf(ss * (1.0f / 256.0f) + 1e-5f);
    float4 g = ((const float4*)gamma)[lane];
    float4 b = ((const float4*)beta)[lane];
    ushort4 o;
    o.x = f2bf(d0 * rstd * g.x + b.x);
    o.y = f2bf(d1 * rstd * g.y + b.y);
    o.z = f2bf(d2 * rstd * g.z + b.z);
    o.w = f2bf(d3 * rstd * g.w + b.w);
    ((ushort4*)(h_bf + (size_t)token * CDIM))[lane] = o;
}

// ---------------- fused Q+K+V projection, 4-way column-split ----------------
// grid (512, 4), 128 thr. Q/K swapped MFMA -> packed 8B stores; V key-columns
// PERMUTED within each 32-key half (slot = quad*8 + nt*4 + r) for flash's
// register-resident P. (round-8/10 version, measured best)
__global__ __launch_bounds__(128) void qkv_kernel(
        const unsigned short* __restrict__ h_bf,
        const unsigned short* __restrict__ wts,
        const float* __restrict__ bq,
        const float* __restrict__ bk,
        const float* __restrict__ bv,
        unsigned short* __restrict__ q_bf,
        unsigned short* __restrict__ k2,
        unsigned short* __restrict__ vt2) {
    __shared__ unsigned short VT[64][VPITCH];   // 8704 B (quarter tile: d in [gy*64, gy*64+64))
    int tid = threadIdx.x;
    int w = tid >> 6, lane = tid & 63, quad = lane >> 4, l16 = lane & 15;
    int blk = blockIdx.x;
    int gy = blockIdx.y;
    int nt0 = gy * 4;
    int tok_base = blk * 64 + w * 32;

    bf16x8 afr[2][8];
    #pragma unroll
    for (int s = 0; s < 2; ++s)
        #pragma unroll
        for (int kk = 0; kk < 8; ++kk)
            afr[s][kk] = *(const bf16x8*)(h_bf + (size_t)(tok_base + s * 16 + l16) * CDIM + kk * 32 + quad * 8);

    // ---- Q (swapped; pre-scaled by SSCALE; 8B packed stores)
    {
        const unsigned short* wq_t = wts;
        #pragma unroll
        for (int ntl = 0; ntl < 4; ++ntl) {
            int nt = nt0 + ntl;
            f32x4 acc0 = {0.f, 0.f, 0.f, 0.f};
            f32x4 acc1 = {0.f, 0.f, 0.f, 0.f};
            #pragma unroll
            for (int kk = 0; kk < 8; ++kk) {
                bf16x8 bfr = *(const bf16x8*)(wq_t + (size_t)(nt * 16 + l16) * CDIM + kk * 32 + quad * 8);
                acc0 = __builtin_amdgcn_mfma_f32_16x16x32_bf16(bfr, afr[0][kk], acc0, 0, 0, 0);
                acc1 = __builtin_amdgcn_mfma_f32_16x16x32_bf16(bfr, afr[1][kk], acc1, 0, 0, 0);
            }
            int d0 = nt * 16 + quad * 4;
            float4 b4 = *(const float4*)(bq + d0);
            ushort4 o0, o1;
            o0.x = f2bf((acc0[0] + b4.x) * SSCALE); o0.y = f2bf((acc0[1] + b4.y) * SSCALE);
            o0.z = f2bf((acc0[2] + b4.z) * SSCALE); o0.w = f2bf((acc0[3] + b4.w) * SSCALE);
            o1.x = f2bf((acc1[0] + b4.x) * SSCALE); o1.y = f2bf((acc1[1] + b4.y) * SSCALE);
            o1.z = f2bf((acc1[2] + b4.z) * SSCALE); o1.w = f2bf((acc1[3] + b4.w) * SSCALE);
            *(ushort4*)(q_bf + (size_t)(tok_base + l16) * CDIM + d0)      = o0;
            *(ushort4*)(q_bf + (size_t)(tok_base + 16 + l16) * CDIM + d0) = o1;
        }
    }
    // ---- K (swapped; into padded tile rows key = w*32 + s*16 + l16)
    {
        const unsigned short* wk_t = wts + CDIM * CDIM;
        unsigned short* kdst = k2 + (size_t)blk * KTILE_SH;
        int key0 = w * 32 + l16;
        #pragma unroll
        for (int ntl = 0; ntl < 4; ++ntl) {
            int nt = nt0 + ntl;
            f32x4 acc0 = {0.f, 0.f, 0.f, 0.f};
            f32x4 acc1 = {0.f, 0.f, 0.f, 0.f};
            #pragma unroll
            for (int kk = 0; kk < 8; ++kk) {
                bf16x8 bfr = *(const bf16x8*)(wk_t + (size_t)(nt * 16 + l16) * CDIM + kk * 32 + quad * 8);
                acc0 = __builtin_amdgcn_mfma_f32_16x16x32_bf16(bfr, afr[0][kk], acc0, 0, 0, 0);
                acc1 = __builtin_amdgcn_mfma_f32_16x16x32_bf16(bfr, afr[1][kk], acc1, 0, 0, 0);
            }
            int d0 = nt * 16 + quad * 4;
            float4 b4 = *(const float4*)(bk + d0);
            ushort4 o0, o1;
            o0.x = f2bf(acc0[0] + b4.x); o0.y = f2bf(acc0[1] + b4.y);
            o0.z = f2bf(acc0[2] + b4.z); o0.w = f2bf(acc0[3] + b4.w);
            o1.x = f2bf(acc1[0] + b4.x); o1.y = f2bf(acc1[1] + b4.y);
            o1.z = f2bf(acc1[2] + b4.z); o1.w = f2bf(acc1[3] + b4.w);
            *(ushort4*)(kdst + (size_t)key0 * KPITCH + d0)        = o0;
            *(ushort4*)(kdst + (size_t)(key0 + 16) * KPITCH + d0) = o1;
        }
    }
    // ---- V (unswapped; transpose through quarter-height LDS, keys permuted)
    {
        const unsigned short* wv_t = wts + 2 * CDIM * CDIM;
        #pragma unroll
        for (int ntl = 0; ntl < 4; ++ntl) {
            int nt = nt0 + ntl;
            f32x4 acc0 = {0.f, 0.f, 0.f, 0.f};
            f32x4 acc1 = {0.f, 0.f, 0.f, 0.f};
            #pragma unroll
            for (int kk = 0; kk < 8; ++kk) {
                bf16x8 bfr = *(const bf16x8*)(wv_t + (size_t)(nt * 16 + l16) * CDIM + kk * 32 + quad * 8);
                acc0 = __builtin_amdgcn_mfma_f32_16x16x32_bf16(afr[0][kk], bfr, acc0, 0, 0, 0);
                acc1 = __builtin_amdgcn_mfma_f32_16x16x32_bf16(afr[1][kk], bfr, acc1, 0, 0, 0);
            }
            int d = nt * 16 + l16;
            float bb = bv[d];
            int dl = ntl * 16 + l16;          // local row (d - gy*64)
            #pragma unroll
            for (int r = 0; r < 4; ++r) {
                VT[dl][w * 32 + quad * 8 + r]     = f2bf(acc0[r] + bb);  // k32 = quad*4+r     (nt=0)
                VT[dl][w * 32 + quad * 8 + 4 + r] = f2bf(acc1[r] + bb);  // k32 = 16+quad*4+r  (nt=1)
            }
        }
    }
    __syncthreads();
    // flat coalesced copy-out: 544 uint4 over 128 threads
    const uint4* src = (const uint4*)(&VT[0][0]);
    uint4* dst = (uint4*)(vt2 + (size_t)blk * VTILE_SH + (size_t)gy * 64 * VPITCH);
    #pragma unroll
    for (int i = 0; i < 4; ++i)
        dst[i * 128 + tid] = src[i * 128 + tid];
    if (tid < 32) dst[512 + tid] = src[512 + tid];
}

// ---------------- Flash attention + fused output projection ------------------
// BYTE-IDENTICAL to round 10 (measured 198.1/196.8 us): distinct __shared__
// arrays, swapped QK^T, register-resident P, permuted V, __syncthreads
// pipeline, s_setprio(1) around MFMA clusters, fused channel-split oproj.
#define DMA_TILE(KS, VS, ktn)                                                        \
    {                                                                                \
        const unsigned short* gk = k2 + (size_t)(b * NT + (ktn)) * KTILE_SH;         \
        const unsigned short* gv = vt2 + (size_t)(b * NT + (ktn)) * VTILE_SH;        \
        for (int c = w; c < TOTCH; c += 8) {                                         \
            if (c < KCH) dma16(gk + c * 512 + lane * 8, &KS[0][0] + c * 512);        \
            else dma16(gv + (c - KCH) * 512 + lane * 8, &VS[0][0] + (c - KCH) * 512);\
        }                                                                            \
    }

#define COMPUTE_TILE(KS, VS)                                                         \
    {                                                                                \
        f32x4 sfr[2][2];                                                             \
        __builtin_amdgcn_s_setprio(1);                                               \
        _Pragma("unroll")                                                            \
        for (int nt = 0; nt < 2; ++nt) {                                             \
            f32x4 a0 = {0.f, 0.f, 0.f, 0.f};                                         \
            f32x4 a1 = {0.f, 0.f, 0.f, 0.f};                                         \
            _Pragma("unroll")                                                        \
            for (int kk = 0; kk < 8; ++kk) {                                         \
                bf16x8 kb = *(const bf16x8*)(&KS[kh * 32 + nt * 16 + l16][kk * 32 + quad * 8]); \
                a0 = __builtin_amdgcn_mfma_f32_16x16x32_bf16(kb, qfr[0][kk], a0, 0, 0, 0);      \
                a1 = __builtin_amdgcn_mfma_f32_16x16x32_bf16(kb, qfr[1][kk], a1, 0, 0, 0);      \
            }                                                                        \
            sfr[0][nt] = a0; sfr[1][nt] = a1;                                        \
        }                                                                            \
        __builtin_amdgcn_s_setprio(0);                                               \
        int4 pwv[2];                                                                 \
        _Pragma("unroll")                                                            \
        for (int s = 0; s < 2; ++s) {                                                \
            unsigned pw[4];                                                          \
            _Pragma("unroll")                                                        \
            for (int nt = 0; nt < 2; ++nt)                                           \
                _Pragma("unroll")                                                    \
                for (int h = 0; h < 2; ++h) {                                        \
                    float plo = exp2f(sfr[s][nt][2 * h]);                            \
                    float phi = exp2f(sfr[s][nt][2 * h + 1]);                        \
                    lacc[s] += plo + phi;                                            \
                    pw[nt * 2 + h] = (__float_as_uint(plo) >> 16)                    \
                                   | (__float_as_uint(phi) & 0xffff0000u);           \
                }                                                                    \
            pwv[s] = make_int4(pw[0], pw[1], pw[2], pw[3]);                          \
        }                                                                            \
        bf16x8 pfr0 = *(bf16x8*)&pwv[0];                                             \
        bf16x8 pfr1 = *(bf16x8*)&pwv[1];                                             \
        __builtin_amdgcn_s_setprio(1);                                               \
        _Pragma("unroll")                                                            \
        for (int nt2 = 0; nt2 < 16; ++nt2) {                                         \
            bf16x8 vb = *(const bf16x8*)(&VS[nt2 * 16 + l16][kh * 32 + quad * 8]);   \
            O[0][nt2] = __builtin_amdgcn_mfma_f32_16x16x32_bf16(pfr0, vb, O[0][nt2], 0, 0, 0);  \
            O[1][nt2] = __builtin_amdgcn_mfma_f32_16x16x32_bf16(pfr1, vb, O[1][nt2], 0, 0, 0);  \
        }                                                                            \
        __builtin_amdgcn_s_setprio(0);                                               \
    }

__global__ __launch_bounds__(512, 2) void flash_kernel(
        const unsigned short* __restrict__ q_bf,
        const unsigned short* __restrict__ k2,
        const unsigned short* __restrict__ vt2,
        const unsigned short* __restrict__ wo_t,
        const float* __restrict__ bo,
        const float* __restrict__ x,
        float* __restrict__ out) {
    __shared__ unsigned short Ks0[BK][KPITCH];    // 33792 B
    __shared__ unsigned short Ks1[BK][KPITCH];    // 33792 B
    __shared__ unsigned short Vs0[CDIM][VPITCH];  // 34816 B
    __shared__ unsigned short Vs1[CDIM][VPITCH];  // 34816 B
    __shared__ float sLbuf[512];                  // 2048 B  (total 139.3 KB)

    int tid = threadIdx.x;
    int w = tid >> 6, lane = tid & 63, quad = lane >> 4, l16 = lane & 15;
    int kh = w >> 2;        // key half of each tile
    int wq = w & 3;         // q-row group (shared with wave w^4)
    int bid = blockIdx.x;
    int b = bid & 7;        // XCD swizzle: same batch -> same XCD L2
    int qtile = bid >> 3;
    int qrow = qtile * BQ + wq * 32;
    const size_t bbase = (size_t)b * NTOK * CDIM;

    bf16x8 qfr[2][8];
    #pragma unroll
    for (int s = 0; s < 2; ++s)
        #pragma unroll
        for (int kk = 0; kk < 8; ++kk)
            qfr[s][kk] = *(const bf16x8*)(q_bf + bbase + (size_t)(qrow + s * 16 + l16) * CDIM + kk * 32 + quad * 8);

    f32x4 O[2][16];
    #pragma unroll
    for (int s = 0; s < 2; ++s)
        #pragma unroll
        for (int i = 0; i < 16; ++i) O[s][i] = (f32x4){0.f, 0.f, 0.f, 0.f};
    float lacc[2] = {0.f, 0.f};   // per-lane: q = s*16+l16, this quad's 8 keys/tile

    DMA_TILE(Ks0, Vs0, 0);
    __syncthreads();

    for (int kt2 = 0; kt2 < NT; kt2 += 2) {
        DMA_TILE(Ks1, Vs1, kt2 + 1);
        COMPUTE_TILE(Ks0, Vs0);
        __syncthreads();
        if (kt2 + 2 < NT) DMA_TILE(Ks0, Vs0, kt2 + 2);
        COMPUTE_TILE(Ks1, Vs1);
        __syncthreads();
    }

    // ---- epilogue 1: combine wave pairs (key halves) through dead LDS buffers
    float* sO = (wq == 0) ? (float*)&Ks0[0][0] : (wq == 1) ? (float*)&Ks1[0][0]
              : (wq == 2) ? (float*)&Vs0[0][0] : (float*)&Vs1[0][0];
    float* sL = sLbuf + wq * 128;    // 2 x 64 floats per pair

    if (kh == 1) {
        #pragma unroll
        for (int s = 0; s < 2; ++s) {
            #pragma unroll
            for (int nt2 = 0; nt2 < 16; ++nt2)
                #pragma unroll
                for (int r = 0; r < 4; ++r)
                    sO[((s * 16 + nt2) * 4 + r) * 64 + lane] = O[s][nt2][r];
            sL[s * 64 + lane] = lacc[s];
        }
    }
    __syncthreads();
    if (kh == 0) {
        float lr[2][4];
        #pragma unroll
        for (int s = 0; s < 2; ++s) {
            float ls = lacc[s] + sL[s * 64 + lane];   // + pair's partial (same lane mapping)
            ls += __shfl_xor(ls, 16, 64);             // sum the 4 quad partials
            ls += __shfl_xor(ls, 32, 64);
            float li = 1.0f / ls;                     // full denom for q = s*16+l16
            #pragma unroll
            for (int r = 0; r < 4; ++r)
                lr[s][r] = __shfl(li, quad * 4 + r, 64);   // denom for O row quad*4+r
        }
        #pragma unroll
        for (int s = 0; s < 2; ++s)
            #pragma unroll
            for (int nt2 = 0; nt2 < 16; ++nt2)
                #pragma unroll
                for (int r = 0; r < 4; ++r)
                    O[s][nt2][r] = (O[s][nt2][r] + sO[((s * 16 + nt2) * 4 + r) * 64 + lane]) * lr[s][r];
    }
    __syncthreads();   // all sO reads done before attn staging overwrites Ks0/Ks1

    // ---- epilogue 2: kh0 waves stage normalized bf16 attn rows.
    // Row t = wq*32 + s*16 + quad*4 + r (0..127): t<64 -> Ks0[t], else Ks1[t-64].
    if (kh == 0) {
        if (wq < 2) {
            #pragma unroll
            for (int s = 0; s < 2; ++s)
                #pragma unroll
                for (int nt2 = 0; nt2 < 16; ++nt2)
                    #pragma unroll
                    for (int r = 0; r < 4; ++r)
                        Ks0[(wq & 1) * 32 + s * 16 + quad * 4 + r][nt2 * 16 + l16] = f2bf(O[s][nt2][r]);
        } else {
            #pragma unroll
            for (int s = 0; s < 2; ++s)
                #pragma unroll
                for (int nt2 = 0; nt2 < 16; ++nt2)
                    #pragma unroll
                    for (int r = 0; r < 4; ++r)
                        Ks1[(wq & 1) * 32 + s * 16 + quad * 4 + r][nt2 * 16 + l16] = f2bf(O[s][nt2][r]);
        }
    }
    __syncthreads();

    // ---- epilogue 3: fused oproj, channel-split. Wave w -> channels
    // nt = 2w, 2w+1 (16 each) for all 128 rows; weight frags hoisted.
    {
        bf16x8 wfr[2][8];
        #pragma unroll
        for (int t = 0; t < 2; ++t)
            #pragma unroll
            for (int kk = 0; kk < 8; ++kk)
                wfr[t][kk] = *(const bf16x8*)(wo_t + (size_t)((w * 2 + t) * 16 + l16) * CDIM + kk * 32 + quad * 8);
        float bb0 = bo[(w * 2 + 0) * 16 + l16];
        float bb1 = bo[(w * 2 + 1) * 16 + l16];
        int tok0 = qtile * BQ;
        #pragma unroll
        for (int rg = 0; rg < 8; ++rg) {
            bf16x8 afr2[8];
            #pragma unroll
            for (int kk = 0; kk < 8; ++kk)
                afr2[kk] = (rg < 4)
                    ? *(const bf16x8*)(&Ks0[rg * 16 + l16][kk * 32 + quad * 8])
                    : *(const bf16x8*)(&Ks1[(rg - 4) * 16 + l16][kk * 32 + quad * 8]);
            f32x4 acc0 = {0.f, 0.f, 0.f, 0.f};
            f32x4 acc1 = {0.f, 0.f, 0.f, 0.f};
            #pragma unroll
            for (int kk = 0; kk < 8; ++kk) {
                acc0 = __builtin_amdgcn_mfma_f32_16x16x32_bf16(afr2[kk], wfr[0][kk], acc0, 0, 0, 0);
                acc1 = __builtin_amdgcn_mfma_f32_16x16x32_bf16(afr2[kk], wfr[1][kk], acc1, 0, 0, 0);
            }
            #pragma unroll
            for (int r = 0; r < 4; ++r) {
                size_t idx = bbase + (size_t)(tok0 + rg * 16 + quad * 4 + r) * CDIM;
                size_t i0 = idx + (w * 2 + 0) * 16 + l16;
                size_t i1 = idx + (w * 2 + 1) * 16 + l16;
                out[i0] = x[i0] + acc0[r] + bb0;
                out[i1] = x[i1] + acc1[r] + bb1;
            }
        }
    }
}

extern "C" void kernel_launch(void* const* d_in, const int* in_sizes, int n_in,
                              void* d_out, int out_size, void* d_ws, size_t ws_size,
                              hipStream_t stream) {
    const float* x     = (const float*)d_in[0];
    const float* gamma = (const float*)d_in[1];
    const float* beta  = (const float*)d_in[2];
    const float* wq    = (const float*)d_in[3];
    const float* bq    = (const float*)d_in[4];
    const float* wk    = (const float*)d_in[5];
    const float* bk    = (const float*)d_in[6];
    const float* wv    = (const float*)d_in[7];
    const float* bv    = (const float*)d_in[8];
    const float* wo    = (const float*)d_in[9];
    const float* bo    = (const float*)d_in[10];
    float* out = (float*)d_out;

    // workspace layout (bytes):
    //   h    @ 0          16,777,216   (LN output)
    //   q    @ 16,777,216 16,777,216
    //   k2   @ 33,554,432 17,301,504   (padded tiled K: 512 tiles x 64 x 264)
    //   vt2  @ 50,855,936 17,825,792   (padded tiled Vt: 512 tiles x 256 x 68, keys permuted)
    //   wt   @ 68,681,728    524,288   (4 transposed bf16 weight matrices)
    char* ws = (char*)d_ws;
    unsigned short* h_bf = (unsigned short*)(ws);
    unsigned short* q_bf = (unsigned short*)(ws + 16777216);
    unsigned short* k2   = (unsigned short*)(ws + 33554432);
    unsigned short* vt2  = (unsigned short*)(ws + 50855936);
    unsigned short* wt   = (unsigned short*)(ws + 68681728);

    prep_kernel<<<TOK / 4 + 64, 256, 0, stream>>>(x, gamma, beta, wq, wk, wv, wo, h_bf, wt);
    qkv_kernel<<<dim3(TOK / 64, 4), 128, 0, stream>>>(h_bf, wt, bq, bk, bv, q_bf, k2, vt2);
    flash_kernel<<<(NTOK / BQ) * NB, 512, 0, stream>>>(
        q_bf, k2, vt2, wt + 3 * (CDIM * CDIM), bo, x, out);
}